// Round 8
// baseline (161.425 us; speedup 1.0000x reference)
//
#include <hip/hip_runtime.h>
#include <stdint.h>

// Problem constants
#define N_B   32
#define C_INN 8
#define L_IN  4096
#define C_LAT 64
#define K_EMB 512
#define E_DIM 64
#define L_OUT 2049                 // (4096 + 2*2 - 4)/2 + 1
#define M_ROWS (N_B * L_OUT)       // 65568

// d_out layout (flat float32, reference return order)
#define SZ_XREC (N_B * C_INN * L_IN)     // 1048576
#define SZ_ZE   (N_B * C_LAT * L_OUT)    // 4196352
#define OFF_XREC 0
#define OFF_ZE   (SZ_XREC)
#define OFF_ZQ   (OFF_ZE + SZ_ZE)
#define OFF_IDX  (OFF_ZQ + SZ_ZE)

typedef short short8 __attribute__((ext_vector_type(8)));
typedef float f32x4  __attribute__((ext_vector_type(4)));

__device__ __forceinline__ unsigned short rne16(float f) {
    unsigned u = __float_as_uint(f);
    return (unsigned short)((u + 0x7FFFu + ((u >> 16) & 1u)) >> 16);
}
__device__ __forceinline__ float frombits16(unsigned short h) {
    return __uint_as_float(((unsigned)h) << 16);
}
// order-preserving float->u32 (monotone for all finite values)
__device__ __forceinline__ unsigned orderbits(float f) {
    unsigned u = __float_as_uint(f);
    return u ^ ((unsigned)((int)u >> 31) | 0x80000000u);
}
__device__ __forceinline__ float unpackf(unsigned ub) {
    unsigned u = (ub & 0x80000000u) ? (ub ^ 0x80000000u) : ~ub;
    return __uint_as_float(u);
}

// ---------------------------------------------------------------------------
// Prep: (a) swizzle codebook into MFMA B-fragment order, split bf16 hi/lo;
// (b) 0.5*||c||^2 per code (same float4 summation order everywhere).
// B8 layout (short8 units): idx = ntile*256 + ks*128 + h*64 + lane.
// ---------------------------------------------------------------------------
__global__ __launch_bounds__(256) void prep_kernel(
    const float* __restrict__ cb, unsigned short* __restrict__ frag,
    float* __restrict__ cbh)
{
    const int ntile = blockIdx.x;        // 0..31
    const int t     = threadIdx.x;
    const int lane  = t & 63;
    const int ks    = (t >> 6) & 1;
    const int h     = t >> 7;            // 0 = hi, 1 = lo
    const int code  = ntile * 16 + (lane & 15);
    const int k0    = ks * 32 + (lane >> 4) * 8;

    const float* src = cb + (size_t)code * E_DIM + k0;
    unsigned short out[8];
#pragma unroll
    for (int j = 0; j < 8; ++j) {
        const float v = src[j];
        const unsigned short hb = rne16(v);
        out[j] = h ? rne16(v - frombits16(hb)) : hb;
    }
    short8 v8;
#pragma unroll
    for (int j = 0; j < 8; ++j) v8[j] = (short)out[j];
    short8* dst = (short8*)(frag + (((size_t)(ntile * 2 + ks) * 2 + h) * 512 + lane * 8));
    *dst = v8;

    if (t < 16) {
        const int c2 = ntile * 16 + t;
        const float4* cp = (const float4*)(cb + (size_t)c2 * E_DIM);
        float s = 0.0f;
#pragma unroll
        for (int d = 0; d < E_DIM / 4; ++d) {
            float4 v = cp[d];
            s += v.x * v.x + v.y * v.y + v.z * v.z + v.w * v.w;
        }
        cbh[c2] = 0.5f * s;
    }
}

// ---------------------------------------------------------------------------
// Fused encode+quantize, round 8.
// R7 post-mortem: latency-bound (MfmaUtil 6.6, VALU 29, occ 26) — per-tile
// L2 loads were never hidden (vmcnt(0) each iter) and the u64 top-2 chain
// added ~100 dependent VALU cyc/tile. This round:
//   - register double-buffered B-fragment prefetch (tile nt+1 in flight
//     while computing nt);
//   - in-loop top-2 kept as f32 dist + i32 code with cndmask (exact
//     lexicographic match to the u64 semantics incl. ties); packed to u64
//     once after the loop;
//   - s_cand row stride 33 (R7's 32 made the argmin scan 32-way conflicted);
//   - min-scan parallelized across all 4 waves;
//   - epilogue codebook gather as 4x dwordx4.
// Screen/rescore semantics identical to R6/R7 (both passed).
// ---------------------------------------------------------------------------
__global__ __launch_bounds__(256, 4) void quantize_kernel(
    const float* __restrict__ x, const float* __restrict__ conv_w,
    const float* __restrict__ conv_b, const float* __restrict__ cb,
    const unsigned short* __restrict__ frag, const float* __restrict__ cbh_ws,
    float* __restrict__ z_e, float* __restrict__ z_q,
    float* __restrict__ idx_out)
{
    __shared__ float s_z[E_DIM][66];                 // [chan][row] pad2 (16.9 KB)
    __shared__ float s_cbh[K_EMB];                   //                  (2 KB)
    __shared__ unsigned long long s_cand[64][33];    // top2/class, pad   (16.9 KB)
    __shared__ unsigned long long s_part[4][64];     // scan partials     (2 KB)
    __shared__ unsigned long long s_final[64];       //                   (0.5 KB)
    __shared__ float s_mstar[64];                    //                   (0.25 KB)

    const int tid  = threadIdx.x;
    const int wave = tid >> 6;
    const int lane = tid & 63;

    s_cbh[tid]       = cbh_ws[tid];
    s_cbh[tid + 256] = cbh_ws[tid + 256];
    if (tid < 64) s_final[tid] = ~0ULL;

    // ---- Phase 1: encode my row's 16 channels ----
    const int  row    = lane;
    const int  r      = blockIdx.x * 64 + row;
    const bool active = (r < M_ROWS);
    const unsigned rr = active ? (unsigned)r : 0u;
    const unsigned n  = rr / 2049u;
    const unsigned tt = rr - n * 2049u;

    {
        const float* xrow = x + (size_t)n * (C_INN * L_IN);
        float xv[C_INN][4];
        const bool fast = (tt >= 1 && tt <= 2047);
        if (fast) {
#pragma unroll
            for (int ci = 0; ci < C_INN; ++ci) {
                float4 v = *(const float4*)(xrow + ci * L_IN + (2 * (int)tt - 2));
                xv[ci][0] = v.x; xv[ci][1] = v.y; xv[ci][2] = v.z; xv[ci][3] = v.w;
            }
        } else {
#pragma unroll
            for (int ci = 0; ci < C_INN; ++ci) {
#pragma unroll
                for (int k = 0; k < 4; ++k) {
                    int xi = 2 * (int)tt - 2 + k;
                    int xc = min(max(xi, 0), L_IN - 1);
                    float v = xrow[ci * L_IN + xc];
                    xv[ci][k] = (xi >= 0 && xi < L_IN) ? v : 0.0f;
                }
            }
        }
        float* zcol = z_e + (size_t)n * (C_LAT * L_OUT) + tt;
#pragma unroll
        for (int j = 0; j < 16; ++j) {
            const int c = wave * 16 + j;             // wave-uniform channel
            float a = conv_b[c];
#pragma unroll
            for (int ci = 0; ci < C_INN; ++ci) {
                const float* wp = conv_w + (c * C_INN + ci) * 4;  // uniform
#pragma unroll
                for (int k = 0; k < 4; ++k) a += xv[ci][k] * wp[k];
            }
            s_z[c][row] = a;                         // 2-way banked: free
            if (active) zcol[(size_t)c * L_OUT] = a;
        }
    }
    __syncthreads();

    // ---- Phase 2: bf16x3 MFMA screen, double-buffered B loads ----
    const int m = lane & 15, q = lane >> 4;
    short8 Ah[2], Al[2];
#pragma unroll
    for (int ks = 0; ks < 2; ++ks) {
#pragma unroll
        for (int j = 0; j < 8; ++j) {
            const float v = s_z[ks * 32 + q * 8 + j][wave * 16 + m];
            const unsigned short hb = rne16(v);
            Ah[ks][j] = (short)hb;
            Al[ks][j] = (short)rne16(v - frombits16(hb));
        }
    }

    float da[4], db[4];
    int   ka[4], kb[4];
#pragma unroll
    for (int r4 = 0; r4 < 4; ++r4) {
        da[r4] = __int_as_float(0x7f800000);   // +inf
        db[r4] = __int_as_float(0x7f800000);
        ka[r4] = 0; kb[r4] = 0;
    }

    const short8* B8 = (const short8*)frag;
    short8 Bc[4], Bn[4];
#pragma unroll
    for (int v = 0; v < 4; ++v) Bc[v] = B8[v * 64 + lane];

    for (int nt = 0; nt < 32; ++nt) {
        if (nt < 31) {
            const int base = (nt + 1) * 256 + lane;
#pragma unroll
            for (int v = 0; v < 4; ++v) Bn[v] = B8[base + v * 64];
        }
        f32x4 acc0 = {0.0f, 0.0f, 0.0f, 0.0f};
        f32x4 acc1 = {0.0f, 0.0f, 0.0f, 0.0f};
        acc0 = __builtin_amdgcn_mfma_f32_16x16x32_bf16(Ah[0], Bc[0], acc0, 0, 0, 0);
        acc1 = __builtin_amdgcn_mfma_f32_16x16x32_bf16(Ah[1], Bc[2], acc1, 0, 0, 0);
        acc0 = __builtin_amdgcn_mfma_f32_16x16x32_bf16(Ah[0], Bc[1], acc0, 0, 0, 0);
        acc1 = __builtin_amdgcn_mfma_f32_16x16x32_bf16(Ah[1], Bc[3], acc1, 0, 0, 0);
        acc0 = __builtin_amdgcn_mfma_f32_16x16x32_bf16(Al[0], Bc[0], acc0, 0, 0, 0);
        acc1 = __builtin_amdgcn_mfma_f32_16x16x32_bf16(Al[1], Bc[2], acc1, 0, 0, 0);

        const int code = nt * 16 + m;                // C col = lane&15
        const float ch = s_cbh[code];
#pragma unroll
        for (int r4 = 0; r4 < 4; ++r4) {             // C row = q*4 + r4
            const float d = ch - (acc0[r4] + acc1[r4]);
            const bool  mv = d < da[r4];
            const float nb = mv ? da[r4] : d;        // displaced / new 2nd
            const int   nk = mv ? ka[r4] : code;
            // lexicographic (dist, code) compare vs current 2nd
            const bool in2 = (nb < db[r4]) || (nb == db[r4] && nk < kb[r4]);
            db[r4] = in2 ? nb : db[r4];
            kb[r4] = in2 ? nk : kb[r4];
            da[r4] = mv ? d : da[r4];
            ka[r4] = mv ? code : ka[r4];
        }
#pragma unroll
        for (int v = 0; v < 4; ++v) Bc[v] = Bn[v];
    }

    // deposit candidates: row = wave*16 + q*4 + r4, slots 2m / 2m+1
#pragma unroll
    for (int r4 = 0; r4 < 4; ++r4) {
        const int rw = wave * 16 + q * 4 + r4;
        s_cand[rw][2 * m + 0] =
            ((unsigned long long)orderbits(da[r4]) << 32) | (unsigned)ka[r4];
        s_cand[rw][2 * m + 1] =
            ((unsigned long long)orderbits(db[r4]) << 32) | (unsigned)kb[r4];
    }
    __syncthreads();

    // per-row approx min: 4-way parallel partial scan, then combine
    {
        unsigned long long mn = ~0ULL;
#pragma unroll
        for (int i = 0; i < 8; ++i) {
            const unsigned long long v = s_cand[lane][wave * 8 + i];
            mn = (v < mn) ? v : mn;
        }
        s_part[wave][lane] = mn;
    }
    __syncthreads();
    if (tid < 64) {
        unsigned long long mn = s_part[0][tid];
        unsigned long long v1 = s_part[1][tid];
        unsigned long long v2 = s_part[2][tid];
        unsigned long long v3 = s_part[3][tid];
        mn = (v1 < mn) ? v1 : mn;
        mn = (v2 < mn) ? v2 : mn;
        mn = (v3 < mn) ? v3 : mn;
        s_mstar[tid] = unpackf((unsigned)(mn >> 32));
    }
    __syncthreads();

    // exact rescore of candidates within m* + eps (expected ~1-2 per row)
    {
        const int rw  = tid >> 2;                    // 4 threads per row
        const float thr = s_mstar[rw] + 0.02f;
#pragma unroll
        for (int j = 0; j < 8; ++j) {
            const int sl = (tid & 3) * 8 + j;        // 0..31
            const unsigned long long cand = s_cand[rw][sl];
            const unsigned code = (unsigned)cand;
            const float fa = unpackf((unsigned)(cand >> 32));
            if (fa <= thr) {                         // +inf empty slots fail
                const float4* c4 = (const float4*)(cb + (size_t)code * E_DIM);
                float dot = 0.0f;
#pragma unroll
                for (int d4 = 0; d4 < 16; ++d4) {
                    const float4 cv = c4[d4];
                    dot += s_z[d4 * 4 + 0][rw] * cv.x +
                           s_z[d4 * 4 + 1][rw] * cv.y +
                           s_z[d4 * 4 + 2][rw] * cv.z +
                           s_z[d4 * 4 + 3][rw] * cv.w;
                }
                const float mex = s_cbh[code] - dot;
                const unsigned long long px =
                    ((unsigned long long)orderbits(mex) << 32) | code;
                atomicMin(&s_final[rw], px);
            }
        }
    }
    __syncthreads();

    // epilogue: z_q gather (4x dwordx4) + coalesced column writes; idx as float
    if (active) {
        const unsigned fk = (unsigned)s_final[row];
        const float4* csel = (const float4*)(cb + (size_t)fk * E_DIM);
        float* zq = z_q + (size_t)n * (C_LAT * L_OUT) + tt;
#pragma unroll
        for (int j4 = 0; j4 < 4; ++j4) {
            const float4 cv = csel[wave * 4 + j4];   // chans wave*16+4j4..+3
            const int c = wave * 16 + j4 * 4;
            zq[(size_t)(c + 0) * L_OUT] = cv.x;
            zq[(size_t)(c + 1) * L_OUT] = cv.y;
            zq[(size_t)(c + 2) * L_OUT] = cv.z;
            zq[(size_t)(c + 3) * L_OUT] = cv.w;
        }
        if (tid < 64) idx_out[r] = (float)fk;
    }
}

// ---------------------------------------------------------------------------
// Decode (ConvTranspose1d), round 8: LDS-staged with full occupancy.
// R5/R7 shape issued 128 separate dword loads/thread (16.8M load-instr,
// ~65k/CU issue cycles -> ~60us). Now: 512 blocks (32 n x 16 s-chunks of 128)
// x 256 threads; block stages z_q[64][s0..s0+128] into LDS (coalesced, 2.1M
// load-instr total), then thread (sl = tid&127, co-half = tid>>7) computes
// 4 co x 2 t from LDS. 33.8KB LDS -> 4 blocks/CU = 16 waves/CU.
// ---------------------------------------------------------------------------
__global__ __launch_bounds__(256) void decode_kernel(
    const float* __restrict__ zq, const float* __restrict__ w,
    const float* __restrict__ b, float* __restrict__ xr)
{
    __shared__ float s_zq[C_LAT][132];   // 129 used, pad to 132 (33.8 KB)

    const int blk   = blockIdx.x;        // 0..511
    const int chunk = blk & 15;
    const int n     = blk >> 4;
    const int s0    = chunk * 128;
    const int tid   = threadIdx.x;
    const int half  = tid >> 7;          // 0/1 (wave-uniform)
    const int sl    = tid & 127;

    const float* zn = zq + (size_t)n * (C_LAT * L_OUT) + s0;
#pragma unroll
    for (int c2 = 0; c2 < C_LAT; c2 += 2) {
        const int c = c2 + half;
        s_zq[c][sl] = zn[(size_t)c * L_OUT + sl];    // 128-consecutive, coalesced
    }
    if (tid < C_LAT) s_zq[tid][128] = zn[(size_t)tid * L_OUT + 128];
    __syncthreads();

    const int co0 = half * 4;                        // wave-uniform
    float e[4], o[4];
#pragma unroll
    for (int j = 0; j < 4; ++j) { e[j] = b[co0 + j]; o[j] = e[j]; }

    for (int ci = 0; ci < C_LAT; ++ci) {
        const float z0 = s_zq[ci][sl];
        const float z1 = s_zq[ci][sl + 1];
        const float* wp = w + (ci * C_INN + co0) * 4;   // wave-uniform -> SGPR
#pragma unroll
        for (int j = 0; j < 4; ++j) {
            e[j] += z0 * wp[4 * j + 2] + z1 * wp[4 * j + 0];
            o[j] += z0 * wp[4 * j + 3] + z1 * wp[4 * j + 1];
        }
    }

    const int s = s0 + sl;
#pragma unroll
    for (int j = 0; j < 4; ++j) {
        float* xrow = xr + ((size_t)(n * C_INN + co0 + j)) * L_IN;
        *(float2*)(xrow + 2 * s) = make_float2(e[j], o[j]);   // 8B aligned
    }
}

// ---------------------------------------------------------------------------
extern "C" void kernel_launch(void* const* d_in, const int* in_sizes, int n_in,
                              void* d_out, int out_size, void* d_ws, size_t ws_size,
                              hipStream_t stream) {
    const float* x        = (const float*)d_in[0];
    const float* conv_w   = (const float*)d_in[1];
    const float* conv_b   = (const float*)d_in[2];
    const float* codebook = (const float*)d_in[3];
    const float* tconv_w  = (const float*)d_in[4];
    const float* tconv_b  = (const float*)d_in[5];

    float* out   = (float*)d_out;
    float* x_rec = out + OFF_XREC;
    float* z_e   = out + OFF_ZE;
    float* z_q   = out + OFF_ZQ;
    float* idxs  = out + OFF_IDX;

    unsigned short* frag = (unsigned short*)d_ws;        // 131072 B
    float*          cbh  = (float*)(frag + 65536);       // + 2048 B

    prep_kernel<<<32, 256, 0, stream>>>(codebook, frag, cbh);
    quantize_kernel<<<(M_ROWS + 63) / 64, 256, 0, stream>>>(
        x, conv_w, conv_b, codebook, frag, cbh, z_e, z_q, idxs);
    decode_kernel<<<512, 256, 0, stream>>>(z_q, tconv_w, tconv_b, x_rec);
}

// Round 9
// 144.126 us; speedup vs baseline: 1.1200x; 1.1200x over previous
//
#include <hip/hip_runtime.h>
#include <stdint.h>

// Problem constants
#define N_B   32
#define C_INN 8
#define L_IN  4096
#define C_LAT 64
#define K_EMB 512
#define E_DIM 64
#define L_OUT 2049                 // (4096 + 2*2 - 4)/2 + 1
#define M_ROWS (N_B * L_OUT)       // 65568

// d_out layout (flat float32, reference return order)
#define SZ_XREC (N_B * C_INN * L_IN)     // 1048576
#define SZ_ZE   (N_B * C_LAT * L_OUT)    // 4196352
#define OFF_XREC 0
#define OFF_ZE   (SZ_XREC)
#define OFF_ZQ   (OFF_ZE + SZ_ZE)
#define OFF_IDX  (OFF_ZQ + SZ_ZE)

typedef short short8 __attribute__((ext_vector_type(8)));
typedef float f32x4  __attribute__((ext_vector_type(4)));

__device__ __forceinline__ unsigned short rne16(float f) {
    unsigned u = __float_as_uint(f);
    return (unsigned short)((u + 0x7FFFu + ((u >> 16) & 1u)) >> 16);
}
__device__ __forceinline__ float frombits16(unsigned short h) {
    return __uint_as_float(((unsigned)h) << 16);
}
// order-preserving float->u32 (monotone for all finite values)
__device__ __forceinline__ unsigned orderbits(float f) {
    unsigned u = __float_as_uint(f);
    return u ^ ((unsigned)((int)u >> 31) | 0x80000000u);
}

// ---------------------------------------------------------------------------
// Prep: (a) swizzle codebook into MFMA B-fragment order, split bf16 hi/lo;
// (b) 0.5*||c||^2 per code (same float4 summation order everywhere).
// B8 layout (short8 units): idx = ntile*256 + ks*128 + hl*64 + lane.
// ---------------------------------------------------------------------------
__global__ __launch_bounds__(256) void prep_kernel(
    const float* __restrict__ cb, unsigned short* __restrict__ frag,
    float* __restrict__ cbh)
{
    const int ntile = blockIdx.x;        // 0..31
    const int t     = threadIdx.x;
    const int lane  = t & 63;
    const int ks    = (t >> 6) & 1;
    const int h     = t >> 7;            // 0 = hi, 1 = lo
    const int code  = ntile * 16 + (lane & 15);
    const int k0    = ks * 32 + (lane >> 4) * 8;

    const float* src = cb + (size_t)code * E_DIM + k0;
    unsigned short out[8];
#pragma unroll
    for (int j = 0; j < 8; ++j) {
        const float v = src[j];
        const unsigned short hb = rne16(v);
        out[j] = h ? rne16(v - frombits16(hb)) : hb;
    }
    short8 v8;
#pragma unroll
    for (int j = 0; j < 8; ++j) v8[j] = (short)out[j];
    short8* dst = (short8*)(frag + (((size_t)(ntile * 2 + ks) * 2 + h) * 512 + lane * 8));
    *dst = v8;

    if (t < 16) {
        const int c2 = ntile * 16 + t;
        const float4* cp = (const float4*)(cb + (size_t)c2 * E_DIM);
        float s = 0.0f;
#pragma unroll
        for (int d = 0; d < E_DIM / 4; ++d) {
            float4 v = cp[d];
            s += v.x * v.x + v.y * v.y + v.z * v.z + v.w * v.w;
        }
        cbh[c2] = 0.5f * s;
    }
}

// ---------------------------------------------------------------------------
// Fused encode+quantize, round 9.
// R6-R8 invariant: screen pinned at ~70us by per-code top-2 VALU (~12/code)
// and redundant B traffic (every wave streamed all 128KB -> 525MB of L2).
// This round:
//  - wave (p = w>>1, h = w&1): row strips 32p..32p+31 x code half h (16 tiles)
//    -> each B tile reused by 2 strips (L2 traffic halved, 12 MFMA / 4 loads);
//  - bias trick: acc init = 0.5||c||^2 + 0.5||z||^2 + 1 with NEGATED A-frags
//    -> MFMA output IS the positive distance; positive floats are u32-monotone;
//  - packed top-2: u32 = dist-bits & ~15 | tile-idx (4b); update = 5 VALU/code
//    (and,or,max,min,min). Code rebuilt from (slot,tile) at rescore. 4-bit
//    trunc error ~2e-4 << 0.02 rescore window;
//  - exact fp32 rescore + ascending-code tie-break unchanged (passed R6-R8).
// ---------------------------------------------------------------------------
__global__ __launch_bounds__(256, 3) void quantize_kernel(
    const float* __restrict__ x, const float* __restrict__ conv_w,
    const float* __restrict__ conv_b, const float* __restrict__ cb,
    const unsigned short* __restrict__ frag, const float* __restrict__ cbh_ws,
    float* __restrict__ z_e, float* __restrict__ z_q,
    float* __restrict__ idx_out)
{
    __shared__ float s_z[E_DIM][66];         // [chan][row] pad2   (16.9 KB)
    __shared__ float s_cbh[K_EMB];           //                    (2 KB)
    __shared__ unsigned s_cand[64][68];      // 64 slots, 16B rows (17.4 KB)
    __shared__ float s_znorm[64];            // 0.5||z||^2 + 1
    __shared__ unsigned s_mstar[64];         // trunc approx-min bits
    __shared__ unsigned long long s_final[64];

    const int tid  = threadIdx.x;
    const int wave = tid >> 6;
    const int lane = tid & 63;
    const int p    = wave >> 1;              // rows 32p..32p+31
    const int h    = wave & 1;               // tiles h*16..h*16+15

    s_cbh[tid]       = cbh_ws[tid];
    s_cbh[tid + 256] = cbh_ws[tid + 256];
    if (tid < 64) s_final[tid] = ~0ULL;

    // ---- Phase 1: encode my row's 16 channels (row = lane, chans wave*16+j) ----
    const int  row    = lane;
    const int  r      = blockIdx.x * 64 + row;
    const bool active = (r < M_ROWS);
    const unsigned rr = active ? (unsigned)r : 0u;
    const unsigned n  = rr / 2049u;
    const unsigned tt = rr - n * 2049u;

    {
        const float* xrow = x + (size_t)n * (C_INN * L_IN);
        float xv[C_INN][4];
        const bool fast = (tt >= 1 && tt <= 2047);
        if (fast) {
#pragma unroll
            for (int ci = 0; ci < C_INN; ++ci) {
                float4 v = *(const float4*)(xrow + ci * L_IN + (2 * (int)tt - 2));
                xv[ci][0] = v.x; xv[ci][1] = v.y; xv[ci][2] = v.z; xv[ci][3] = v.w;
            }
        } else {
#pragma unroll
            for (int ci = 0; ci < C_INN; ++ci) {
#pragma unroll
                for (int k = 0; k < 4; ++k) {
                    int xi = 2 * (int)tt - 2 + k;
                    int xc = min(max(xi, 0), L_IN - 1);
                    float v = xrow[ci * L_IN + xc];
                    xv[ci][k] = (xi >= 0 && xi < L_IN) ? v : 0.0f;
                }
            }
        }
        float* zcol = z_e + (size_t)n * (C_LAT * L_OUT) + tt;
#pragma unroll
        for (int j = 0; j < 16; ++j) {
            const int c = wave * 16 + j;             // wave-uniform channel
            float a = conv_b[c];
#pragma unroll
            for (int ci = 0; ci < C_INN; ++ci) {
                const float* wp = conv_w + (c * C_INN + ci) * 4;  // uniform
#pragma unroll
                for (int k = 0; k < 4; ++k) a += xv[ci][k] * wp[k];
            }
            s_z[c][row] = a;
            if (active) zcol[(size_t)c * L_OUT] = a;
        }
    }
    __syncthreads();

    // ---- row norms (one thread per row) + negated A-fragments (all threads) ----
    if (tid < 64) {
        float s = 0.0f;
#pragma unroll 8
        for (int c = 0; c < E_DIM; ++c) {
            const float v = s_z[c][tid];
            s += v * v;
        }
        s_znorm[tid] = 0.5f * s + 1.0f;
    }

    const int m = lane & 15, q = lane >> 4;
    short8 Ah[2][2], Al[2][2];               // [strip][ks], A = -z
#pragma unroll
    for (int st = 0; st < 2; ++st) {
        const int arow = p * 32 + st * 16 + m;
#pragma unroll
        for (int ks = 0; ks < 2; ++ks) {
#pragma unroll
            for (int j = 0; j < 8; ++j) {
                const float v = -s_z[ks * 32 + q * 8 + j][arow];
                const unsigned short hb = rne16(v);
                Ah[st][ks][j] = (short)hb;
                Al[st][ks][j] = (short)rne16(v - frombits16(hb));
            }
        }
    }
    __syncthreads();

    float Kn[2][4];
#pragma unroll
    for (int st = 0; st < 2; ++st)
#pragma unroll
        for (int r4 = 0; r4 < 4; ++r4)
            Kn[st][r4] = s_znorm[p * 32 + st * 16 + q * 4 + r4];

    // ---- screen: 16 tiles of half h, register prefetch depth 1 ----
    unsigned ca[2][4], cb2[2][4];
#pragma unroll
    for (int st = 0; st < 2; ++st)
#pragma unroll
        for (int r4 = 0; r4 < 4; ++r4) { ca[st][r4] = 0xFFFFFFFFu; cb2[st][r4] = 0xFFFFFFFFu; }

    const short8* B8 = (const short8*)frag;
    short8 Bc[4], Bn[4];
    {
        const int base = (h * 16) * 256 + lane;
#pragma unroll
        for (int v = 0; v < 4; ++v) Bc[v] = B8[base + v * 64];
    }

    for (int t = 0; t < 16; ++t) {
        if (t < 15) {
            const int base = (h * 16 + t + 1) * 256 + lane;
#pragma unroll
            for (int v = 0; v < 4; ++v) Bn[v] = B8[base + v * 64];
        }
        const int code = (h * 16 + t) * 16 + m;
        const float chv = s_cbh[code];

        f32x4 accA = {chv + Kn[0][0], chv + Kn[0][1], chv + Kn[0][2], chv + Kn[0][3]};
        f32x4 accB = {chv + Kn[1][0], chv + Kn[1][1], chv + Kn[1][2], chv + Kn[1][3]};
        accA = __builtin_amdgcn_mfma_f32_16x16x32_bf16(Ah[0][0], Bc[0], accA, 0, 0, 0);
        accB = __builtin_amdgcn_mfma_f32_16x16x32_bf16(Ah[1][0], Bc[0], accB, 0, 0, 0);
        accA = __builtin_amdgcn_mfma_f32_16x16x32_bf16(Ah[0][0], Bc[1], accA, 0, 0, 0);
        accB = __builtin_amdgcn_mfma_f32_16x16x32_bf16(Ah[1][0], Bc[1], accB, 0, 0, 0);
        accA = __builtin_amdgcn_mfma_f32_16x16x32_bf16(Al[0][0], Bc[0], accA, 0, 0, 0);
        accB = __builtin_amdgcn_mfma_f32_16x16x32_bf16(Al[1][0], Bc[0], accB, 0, 0, 0);
        accA = __builtin_amdgcn_mfma_f32_16x16x32_bf16(Ah[0][1], Bc[2], accA, 0, 0, 0);
        accB = __builtin_amdgcn_mfma_f32_16x16x32_bf16(Ah[1][1], Bc[2], accB, 0, 0, 0);
        accA = __builtin_amdgcn_mfma_f32_16x16x32_bf16(Ah[0][1], Bc[3], accA, 0, 0, 0);
        accB = __builtin_amdgcn_mfma_f32_16x16x32_bf16(Ah[1][1], Bc[3], accB, 0, 0, 0);
        accA = __builtin_amdgcn_mfma_f32_16x16x32_bf16(Al[0][1], Bc[2], accA, 0, 0, 0);
        accB = __builtin_amdgcn_mfma_f32_16x16x32_bf16(Al[1][1], Bc[2], accB, 0, 0, 0);

#pragma unroll
        for (int st = 0; st < 2; ++st) {
            const f32x4 acc = st ? accB : accA;
#pragma unroll
            for (int r4 = 0; r4 < 4; ++r4) {
                const unsigned xx = (__float_as_uint(acc[r4]) & 0xFFFFFFF0u) | (unsigned)t;
                const unsigned mx = max(ca[st][r4], xx);
                ca[st][r4]  = min(ca[st][r4], xx);
                cb2[st][r4] = min(cb2[st][r4], mx);
            }
        }
#pragma unroll
        for (int v = 0; v < 4; ++v) Bc[v] = Bn[v];
    }

    // deposit: row = 32p + 16st + 4q + r4, slots h*32 + 2m (+1)
#pragma unroll
    for (int st = 0; st < 2; ++st)
#pragma unroll
        for (int r4 = 0; r4 < 4; ++r4) {
            const int rw = p * 32 + st * 16 + q * 4 + r4;
            s_cand[rw][h * 32 + 2 * m + 0] = ca[st][r4];
            s_cand[rw][h * 32 + 2 * m + 1] = cb2[st][r4];
        }
    __syncthreads();

    // per-row approx min over the 64 candidate slots
    if (tid < 64) {
        unsigned mn = 0xFFFFFFFFu;
#pragma unroll 8
        for (int i = 0; i < 64; ++i) mn = min(mn, s_cand[tid][i]);
        s_mstar[tid] = mn & 0xFFFFFFF0u;
    }
    __syncthreads();

    // exact rescore of candidates within m* + eps (expected ~1-2 per row)
    {
        const int rw  = tid >> 2;                    // 4 threads per row
        const float thr = __uint_as_float(s_mstar[rw]) + 0.02f;
#pragma unroll
        for (int j = 0; j < 16; ++j) {
            const int sl = (tid & 3) * 16 + j;       // 0..63
            const unsigned cand = s_cand[rw][sl];
            const float fd = __uint_as_float(cand & 0xFFFFFFF0u);
            if (fd <= thr) {
                // slot -> (half = sl>>5, class m = (sl>>1)&15), tile = cand&15
                const unsigned code =
                    (((unsigned)(sl >> 5) * 16u + (cand & 15u)) * 16u) +
                    (unsigned)((sl >> 1) & 15);
                const float4* c4 = (const float4*)(cb + (size_t)code * E_DIM);
                float dot = 0.0f;
#pragma unroll
                for (int d4 = 0; d4 < 16; ++d4) {
                    const float4 cv = c4[d4];
                    dot += s_z[d4 * 4 + 0][rw] * cv.x +
                           s_z[d4 * 4 + 1][rw] * cv.y +
                           s_z[d4 * 4 + 2][rw] * cv.z +
                           s_z[d4 * 4 + 3][rw] * cv.w;
                }
                const float mex = s_cbh[code] - dot;
                const unsigned long long px =
                    ((unsigned long long)orderbits(mex) << 32) | code;
                atomicMin(&s_final[rw], px);
            }
        }
    }
    __syncthreads();

    // epilogue: z_q gather (4x dwordx4) + coalesced column writes; idx as float
    if (active) {
        const unsigned fk = (unsigned)s_final[row];
        const float4* csel = (const float4*)(cb + (size_t)fk * E_DIM);
        float* zq = z_q + (size_t)n * (C_LAT * L_OUT) + tt;
#pragma unroll
        for (int j4 = 0; j4 < 4; ++j4) {
            const float4 cv = csel[wave * 4 + j4];   // chans wave*16+4j4..+3
            const int c = wave * 16 + j4 * 4;
            zq[(size_t)(c + 0) * L_OUT] = cv.x;
            zq[(size_t)(c + 1) * L_OUT] = cv.y;
            zq[(size_t)(c + 2) * L_OUT] = cv.z;
            zq[(size_t)(c + 3) * L_OUT] = cv.w;
        }
        if (tid < 64) idx_out[r] = (float)fk;
    }
}

// ---------------------------------------------------------------------------
// Decode (ConvTranspose1d) — exact R7 shape (best measured residual):
// 1024 blocks (n x 2 co-groups x 16 s-chunks) x 128 thr, 4 co per block.
// ---------------------------------------------------------------------------
__global__ __launch_bounds__(128) void decode_kernel(
    const float* __restrict__ zq, const float* __restrict__ w,
    const float* __restrict__ b, float* __restrict__ xr)
{
    const int blk   = blockIdx.x;           // 0..1023
    const int chunk = blk & 15;
    const int cog   = (blk >> 4) & 1;
    const int n     = blk >> 5;
    const int s     = chunk * 128 + threadIdx.x;   // 0..2047
    const int co0   = cog * 4;

    const float* zn = zq + (size_t)n * (C_LAT * L_OUT) + s;
    float e[4], o[4];
#pragma unroll
    for (int j = 0; j < 4; ++j) { e[j] = b[co0 + j]; o[j] = e[j]; }

#pragma unroll 4
    for (int ci = 0; ci < C_LAT; ++ci) {
        const float z0 = zn[(size_t)ci * L_OUT];
        const float z1 = zn[(size_t)ci * L_OUT + 1];
        const float* wp = w + (ci * C_INN + co0) * 4;   // wave-uniform
#pragma unroll
        for (int j = 0; j < 4; ++j) {
            e[j] += z0 * wp[4 * j + 2] + z1 * wp[4 * j + 0];
            o[j] += z0 * wp[4 * j + 3] + z1 * wp[4 * j + 1];
        }
    }

#pragma unroll
    for (int j = 0; j < 4; ++j) {
        float* xrow = xr + ((size_t)(n * C_INN + co0 + j)) * L_IN;
        *(float2*)(xrow + 2 * s) = make_float2(e[j], o[j]);   // 8B aligned
    }
}

// ---------------------------------------------------------------------------
extern "C" void kernel_launch(void* const* d_in, const int* in_sizes, int n_in,
                              void* d_out, int out_size, void* d_ws, size_t ws_size,
                              hipStream_t stream) {
    const float* x        = (const float*)d_in[0];
    const float* conv_w   = (const float*)d_in[1];
    const float* conv_b   = (const float*)d_in[2];
    const float* codebook = (const float*)d_in[3];
    const float* tconv_w  = (const float*)d_in[4];
    const float* tconv_b  = (const float*)d_in[5];

    float* out   = (float*)d_out;
    float* x_rec = out + OFF_XREC;
    float* z_e   = out + OFF_ZE;
    float* z_q   = out + OFF_ZQ;
    float* idxs  = out + OFF_IDX;

    unsigned short* frag = (unsigned short*)d_ws;        // 131072 B
    float*          cbh  = (float*)(frag + 65536);       // + 2048 B

    prep_kernel<<<32, 256, 0, stream>>>(codebook, frag, cbh);
    quantize_kernel<<<(M_ROWS + 63) / 64, 256, 0, stream>>>(
        x, conv_w, conv_b, codebook, frag, cbh, z_e, z_q, idxs);
    decode_kernel<<<1024, 128, 0, stream>>>(z_q, tconv_w, tconv_b, x_rec);
}